// Round 4
// baseline (560.378 us; speedup 1.0000x reference)
//
#include <hip/hip_runtime.h>

namespace {

constexpr int N_NODES = 50000;
constexpr int E_RAW   = 800000;
constexpr int E_TOT   = E_RAW + N_NODES;   // + self loops
constexpr float SLOPE = 0.2f;
constexpr float EPS_V = 1e-16f;
constexpr int SCAN_BLOCKS = (N_NODES + 255) / 256;   // 196
constexpr int AGG_NBK = 256;                         // agg_k blocks per slice

// ---- GEMM: O[n,0:128] = X[n,0:128] @ W[128,128] + fused attn s/d epilogue ----
template<int H>
__global__ __launch_bounds__(256) void gemm128_k(
    const float* __restrict__ X, const float* __restrict__ W,
    float* __restrict__ O, int nrows,
    const float* __restrict__ a_src, const float* __restrict__ a_dst,
    float* __restrict__ sb, float* __restrict__ db)
{
    __shared__ float Ws[64][128];    // [k][col]
    __shared__ float XsT[64][128];   // [k][row]
    const int t  = threadIdx.x;
    const int tx = t & 15;
    const int ty = t >> 4;
    const int row0 = blockIdx.x * 128;

    float acc[8][8];
    #pragma unroll
    for (int i = 0; i < 8; ++i)
        #pragma unroll
        for (int j = 0; j < 8; ++j) acc[i][j] = 0.f;

    for (int kh = 0; kh < 2; ++kh) {
        const float4* Wv = (const float4*)(W + (size_t)kh * 64 * 128);
        float4* Wsv = (float4*)&Ws[0][0];
        #pragma unroll
        for (int i = 0; i < 8; ++i) Wsv[t + 256 * i] = Wv[t + 256 * i];
        #pragma unroll
        for (int ii = 0; ii < 8; ++ii) {
            int idx = t + 256 * ii;
            int r   = idx & 127;
            int q   = idx >> 7;
            int gr  = row0 + r;
            float4 v = make_float4(0.f, 0.f, 0.f, 0.f);
            if (gr < nrows) v = *(const float4*)(X + (size_t)gr * 128 + kh * 64 + q * 4);
            XsT[q * 4 + 0][r] = v.x;
            XsT[q * 4 + 1][r] = v.y;
            XsT[q * 4 + 2][r] = v.z;
            XsT[q * 4 + 3][r] = v.w;
        }
        __syncthreads();
        #pragma unroll 4
        for (int k = 0; k < 64; ++k) {
            float4 a0 = *(const float4*)&XsT[k][ty * 8];
            float4 a1 = *(const float4*)&XsT[k][ty * 8 + 4];
            float4 b0 = *(const float4*)&Ws[k][tx * 8];
            float4 b1 = *(const float4*)&Ws[k][tx * 8 + 4];
            float av[8] = {a0.x, a0.y, a0.z, a0.w, a1.x, a1.y, a1.z, a1.w};
            float bv[8] = {b0.x, b0.y, b0.z, b0.w, b1.x, b1.y, b1.z, b1.w};
            #pragma unroll
            for (int i = 0; i < 8; ++i)
                #pragma unroll
                for (int j = 0; j < 8; ++j)
                    acc[i][j] = fmaf(av[i], bv[j], acc[i][j]);
        }
        __syncthreads();
    }
    // store O
    #pragma unroll
    for (int i = 0; i < 8; ++i) {
        int gr = row0 + ty * 8 + i;
        if (gr < nrows) {
            *(float4*)(O + (size_t)gr * 128 + tx * 8) =
                make_float4(acc[i][0], acc[i][1], acc[i][2], acc[i][3]);
            *(float4*)(O + (size_t)gr * 128 + tx * 8 + 4) =
                make_float4(acc[i][4], acc[i][5], acc[i][6], acc[i][7]);
        }
    }
    // fused attn coefficients: s[row,h] = <h_row, a_src[h]>, d likewise
    float as_c[8], ad_c[8];
    #pragma unroll
    for (int j = 0; j < 8; ++j) {
        as_c[j] = a_src[tx * 8 + j];
        ad_c[j] = a_dst[tx * 8 + j];
    }
    #pragma unroll
    for (int i = 0; i < 8; ++i) {
        float sp = 0.f, dp = 0.f;
        #pragma unroll
        for (int j = 0; j < 8; ++j) {
            sp = fmaf(acc[i][j], as_c[j], sp);
            dp = fmaf(acc[i][j], ad_c[j], dp);
        }
        int gr = row0 + ty * 8 + i;
        if (H == 4) {
            sp += __shfl_xor(sp, 1, 64); sp += __shfl_xor(sp, 2, 64);
            dp += __shfl_xor(dp, 1, 64); dp += __shfl_xor(dp, 2, 64);
            if ((tx & 3) == 0 && gr < nrows) {
                sb[gr * 4 + (tx >> 2)] = sp;
                db[gr * 4 + (tx >> 2)] = dp;
            }
        } else {
            sp += __shfl_xor(sp, 1, 64); sp += __shfl_xor(sp, 2, 64);
            sp += __shfl_xor(sp, 4, 64); sp += __shfl_xor(sp, 8, 64);
            dp += __shfl_xor(dp, 1, 64); dp += __shfl_xor(dp, 2, 64);
            dp += __shfl_xor(dp, 4, 64); dp += __shfl_xor(dp, 8, 64);
            if (tx == 0 && gr < nrows) { sb[gr] = sp; db[gr] = dp; }
        }
    }
}

__device__ __forceinline__ void edge_endpoints(const int* __restrict__ ei, int e,
                                               int& src, int& dst)
{
    if (e < E_RAW) { src = ei[e]; dst = ei[E_RAW + e]; }
    else           { src = e - E_RAW; dst = src; }
}

// ============ CSR build (once per call) ============
__global__ __launch_bounds__(256) void csr_count_k(
    const int* __restrict__ ei, int* __restrict__ cnt)
{
    int e = blockIdx.x * 256 + threadIdx.x;
    if (e >= E_TOT) return;
    int src, dst;
    edge_endpoints(ei, e, src, dst);
    atomicAdd(&cnt[dst], 1);
}

__device__ __forceinline__ int block_incl_scan_256(int x, int* wsum) {
    int lane = threadIdx.x & 63, wid = threadIdx.x >> 6;
    #pragma unroll
    for (int off = 1; off < 64; off <<= 1) {
        int y = __shfl_up(x, off, 64);
        if (lane >= off) x += y;
    }
    if (lane == 63) wsum[wid] = x;
    __syncthreads();
    int add = 0;
    #pragma unroll
    for (int w = 0; w < 4; ++w) if (w < wid) add += wsum[w];
    return x + add;
}

__global__ __launch_bounds__(256) void scan1_k(
    const int* __restrict__ cnt, int* __restrict__ rp, int* __restrict__ bsum)
{
    __shared__ int wsum[4];
    int i = blockIdx.x * 256 + threadIdx.x;
    int x = (i < N_NODES) ? cnt[i] : 0;
    int incl = block_incl_scan_256(x, wsum);
    if (i < N_NODES) rp[i] = incl;
    if (threadIdx.x == 255) bsum[blockIdx.x] = incl;
}

__global__ __launch_bounds__(256) void scan2_k(int* __restrict__ bsum)
{
    __shared__ int wsum[4];
    int t = threadIdx.x;
    int x = (t < SCAN_BLOCKS) ? bsum[t] : 0;
    int incl = block_incl_scan_256(x, wsum);
    if (t < SCAN_BLOCKS) bsum[t] = incl - x;   // exclusive
}

__global__ __launch_bounds__(256) void scan3_k(
    const int* __restrict__ cnt, int* __restrict__ rp,
    const int* __restrict__ bsum, int* __restrict__ cursor)
{
    int i = blockIdx.x * 256 + threadIdx.x;
    if (i < N_NODES) {
        int v = rp[i] + bsum[blockIdx.x] - cnt[i];
        rp[i] = v;
        cursor[i] = v;
    }
    if (i == 0) rp[N_NODES] = E_TOT;
}

__global__ __launch_bounds__(256) void csr_scatter_k(
    const int* __restrict__ ei, int* __restrict__ cursor, int* __restrict__ csr_src)
{
    int e = blockIdx.x * 256 + threadIdx.x;
    if (e >= E_TOT) return;
    int src, dst;
    edge_endpoints(ei, e, src, dst);
    int pos = atomicAdd(&cursor[dst], 1);
    csr_src[pos] = src;
}

// ============ alpha_k: per-node softmax -> normalized alpha per edge ============
// one wave per node; exp computed once per (edge, head); alpha = p/(den+EPS)
template<int H>
__global__ __launch_bounds__(256) void alpha_k(
    const int* __restrict__ rp, const int* __restrict__ csr_src,
    const float* __restrict__ sb, const float* __restrict__ db,
    float* __restrict__ alpha)
{
    const int wv = (blockIdx.x * 256 + threadIdx.x) >> 6;
    const int lane = threadIdx.x & 63;
    if (wv >= N_NODES) return;
    const int n = wv;
    const int beg = rp[n], end = rp[n + 1];
    const int deg = end - beg;

    float dn[H];
    #pragma unroll
    for (int h = 0; h < H; ++h) dn[h] = db[n * H + h];

    if (deg <= 64) {
        // single-chunk fast path: everything stays in registers
        const int i = beg + lane;
        const bool act = lane < deg;
        int s = act ? csr_src[i] : 0;
        float v[H];
        if (H == 4) {
            float4 s4 = ((const float4*)sb)[s];
            v[0] = s4.x + dn[0]; v[1] = s4.y + dn[1];
            v[2] = s4.z + dn[2]; v[3] = s4.w + dn[3];
        } else {
            v[0] = sb[s] + dn[0];
        }
        float m[H], p[H], den[H];
        #pragma unroll
        for (int h = 0; h < H; ++h) {
            v[h] = v[h] > 0.f ? v[h] : SLOPE * v[h];
            m[h] = act ? v[h] : -3.0e38f;
        }
        #pragma unroll
        for (int off = 1; off < 64; off <<= 1)
            #pragma unroll
            for (int h = 0; h < H; ++h)
                m[h] = fmaxf(m[h], __shfl_xor(m[h], off, 64));
        #pragma unroll
        for (int h = 0; h < H; ++h) {
            p[h] = act ? __expf(v[h] - m[h]) : 0.f;
            den[h] = p[h];
        }
        #pragma unroll
        for (int off = 1; off < 64; off <<= 1)
            #pragma unroll
            for (int h = 0; h < H; ++h)
                den[h] += __shfl_xor(den[h], off, 64);
        if (act) {
            if (H == 4) {
                float4 a4 = make_float4(p[0] / (den[0] + EPS_V), p[1] / (den[1] + EPS_V),
                                        p[2] / (den[2] + EPS_V), p[3] / (den[3] + EPS_V));
                ((float4*)alpha)[i] = a4;
            } else {
                alpha[i] = p[0] / (den[0] + EPS_V);
            }
        }
    } else {
        // generic 3-pass path (rare for this graph)
        float m[H];
        #pragma unroll
        for (int h = 0; h < H; ++h) m[h] = -3.0e38f;
        for (int i = beg + lane; i < end; i += 64) {
            int s = csr_src[i];
            #pragma unroll
            for (int h = 0; h < H; ++h) {
                float v = sb[s * H + h] + dn[h];
                v = v > 0.f ? v : SLOPE * v;
                m[h] = fmaxf(m[h], v);
            }
        }
        #pragma unroll
        for (int off = 1; off < 64; off <<= 1)
            #pragma unroll
            for (int h = 0; h < H; ++h)
                m[h] = fmaxf(m[h], __shfl_xor(m[h], off, 64));
        float den[H];
        #pragma unroll
        for (int h = 0; h < H; ++h) den[h] = 0.f;
        for (int i = beg + lane; i < end; i += 64) {
            int s = csr_src[i];
            #pragma unroll
            for (int h = 0; h < H; ++h) {
                float v = sb[s * H + h] + dn[h];
                v = v > 0.f ? v : SLOPE * v;
                den[h] += __expf(v - m[h]);
            }
        }
        #pragma unroll
        for (int off = 1; off < 64; off <<= 1)
            #pragma unroll
            for (int h = 0; h < H; ++h)
                den[h] += __shfl_xor(den[h], off, 64);
        float inv[H];
        #pragma unroll
        for (int h = 0; h < H; ++h) inv[h] = 1.f / (den[h] + EPS_V);
        for (int i = beg + lane; i < end; i += 64) {
            int s = csr_src[i];
            #pragma unroll
            for (int h = 0; h < H; ++h) {
                float v = sb[s * H + h] + dn[h];
                v = v > 0.f ? v : SLOPE * v;
                alpha[i * H + h] = __expf(v - m[h]) * inv[h];
            }
        }
    }
}

// ============ agg_k: channel-sliced weighted aggregation ============
// slice = blockIdx & 7 -> under round-robin dispatch each XCD's h-slice
// working set is 50000*64B = 3.2MB (fits private 4MB L2). Correct regardless
// of actual XCD mapping. Wave layout: 16 edge-slots x 4 float4 lanes.
template<int H, bool RELU>
__global__ __launch_bounds__(256) void agg_k(
    const int* __restrict__ rp, const int* __restrict__ csr_src,
    const float* __restrict__ alpha, const float* __restrict__ Hh,
    const float* __restrict__ bias, float* __restrict__ outv)
{
    const int slice = blockIdx.x & 7;
    const int kb    = blockIdx.x >> 3;            // 0..AGG_NBK-1
    const int w     = threadIdx.x >> 6;           // wave in block (0..3)
    const int lane  = threadIdx.x & 63;
    const int f     = lane & 3;                   // float4 within slice
    const int slot  = lane >> 2;                  // 16 edge slots
    const int h     = (slice * 16) / (128 / H);
    const float4* h4 = (const float4*)Hh;
    const float4 b4 = ((const float4*)bias)[slice * 4 + f];
    const int wstride = AGG_NBK * 4;

    for (int n = kb * 4 + w; n < N_NODES; n += wstride) {
        const int beg = rp[n], end = rp[n + 1];
        float4 acc = make_float4(0.f, 0.f, 0.f, 0.f);
        for (int i = beg + slot; i < end; i += 16) {
            int s = csr_src[i];
            float a = alpha[i * H + h];
            float4 hv = h4[(size_t)s * 32 + slice * 4 + f];
            acc.x = fmaf(a, hv.x, acc.x);
            acc.y = fmaf(a, hv.y, acc.y);
            acc.z = fmaf(a, hv.z, acc.z);
            acc.w = fmaf(a, hv.w, acc.w);
        }
        #pragma unroll
        for (int off = 4; off < 64; off <<= 1) {
            acc.x += __shfl_xor(acc.x, off, 64);
            acc.y += __shfl_xor(acc.y, off, 64);
            acc.z += __shfl_xor(acc.z, off, 64);
            acc.w += __shfl_xor(acc.w, off, 64);
        }
        if (slot == 0) {
            float ox = acc.x + b4.x, oy = acc.y + b4.y;
            float oz = acc.z + b4.z, ow = acc.w + b4.w;
            if (RELU) {
                ox = fmaxf(ox, 0.f); oy = fmaxf(oy, 0.f);
                oz = fmaxf(oz, 0.f); ow = fmaxf(ow, 0.f);
            }
            *(float4*)(outv + (size_t)n * 128 + slice * 16 + f * 4) =
                make_float4(ox, oy, oz, ow);
        }
    }
}

template<int H, bool RELU>
void run_layer(const float* xin, const float* Wm, const float* as_, const float* ad_,
               const float* bias, const int* rp, const int* csr_src,
               float* hbuf, float* outv, float* sb, float* db, float* alpha,
               hipStream_t stream)
{
    gemm128_k<H><<<(N_NODES + 127) / 128, 256, 0, stream>>>(
        xin, Wm, hbuf, N_NODES, as_, ad_, sb, db);
    alpha_k<H><<<(N_NODES * 64 + 255) / 256, 256, 0, stream>>>(
        rp, csr_src, sb, db, alpha);
    agg_k<H, RELU><<<AGG_NBK * 8, 256, 0, stream>>>(
        rp, csr_src, alpha, hbuf, bias, outv);
}

} // namespace

extern "C" void kernel_launch(void* const* d_in, const int* in_sizes, int n_in,
                              void* d_out, int out_size, void* d_ws, size_t ws_size,
                              hipStream_t stream)
{
    (void)in_sizes; (void)n_in; (void)out_size; (void)ws_size;
    const float* x   = (const float*)d_in[0];
    const int*   ei  = (const int*)d_in[1];
    const float* W0  = (const float*)d_in[2];
    const float* as0 = (const float*)d_in[3];
    const float* ad0 = (const float*)d_in[4];
    const float* b0  = (const float*)d_in[5];
    const float* W1  = (const float*)d_in[6];
    const float* as1 = (const float*)d_in[7];
    const float* ad1 = (const float*)d_in[8];
    const float* b1  = (const float*)d_in[9];
    const float* W2  = (const float*)d_in[10];
    const float* as2 = (const float*)d_in[11];
    const float* ad2 = (const float*)d_in[12];
    const float* b2  = (const float*)d_in[13];
    float* out = (float*)d_out;

    char* p = (char*)d_ws;
    float* A       = (float*)p;  p += (size_t)N_NODES * 128 * 4;   // h buffer
    float* B       = (float*)p;  p += (size_t)N_NODES * 128 * 4;   // x1 / scratch
    float* sb      = (float*)p;  p += (size_t)N_NODES * 4 * 4;
    float* db      = (float*)p;  p += (size_t)N_NODES * 4 * 4;
    int*   cnt     = (int*)p;    p += (size_t)N_NODES * 4;
    int*   rp      = (int*)p;    p += (size_t)(N_NODES + 1) * 4;
    int*   cursor  = (int*)p;    p += (size_t)N_NODES * 4;
    int*   bsum    = (int*)p;    p += (size_t)SCAN_BLOCKS * 4;
    int*   csr_src = (int*)p;    p += (size_t)E_TOT * 4;
    float* alpha   = (float*)p;  p += (size_t)E_TOT * 4 * 4;

    const int EB = (E_TOT + 255) / 256;

    // ---- CSR build (once; reused by all 3 layers) ----
    hipMemsetAsync(cnt, 0, (size_t)N_NODES * 4, stream);
    csr_count_k<<<EB, 256, 0, stream>>>(ei, cnt);
    scan1_k<<<SCAN_BLOCKS, 256, 0, stream>>>(cnt, rp, bsum);
    scan2_k<<<1, 256, 0, stream>>>(bsum);
    scan3_k<<<SCAN_BLOCKS, 256, 0, stream>>>(cnt, rp, bsum, cursor);
    csr_scatter_k<<<EB, 256, 0, stream>>>(ei, cursor, csr_src);

    // Layer 0: x -> h(A); agg -> B (ReLU)
    run_layer<4, true >(x,   W0, as0, ad0, b0, rp, csr_src, A, B,   sb, db, alpha, stream);
    // Layer 1: B -> h(A); agg -> out (ReLU)
    run_layer<4, true >(B,   W1, as1, ad1, b1, rp, csr_src, A, out, sb, db, alpha, stream);
    // Layer 2 (H=1): out -> h(A); agg -> out (no ReLU)
    run_layer<1, false>(out, W2, as2, ad2, b2, rp, csr_src, A, out, sb, db, alpha, stream);
}

// Round 5
// 376.656 us; speedup vs baseline: 1.4878x; 1.4878x over previous
//
#include <hip/hip_runtime.h>

namespace {

constexpr int N_NODES = 50000;
constexpr int E_RAW   = 800000;
constexpr int E_TOT   = E_RAW + N_NODES;   // + self loops
constexpr float SLOPE = 0.2f;
constexpr float EPS_V = 1e-16f;
constexpr int SCAN_BLOCKS = (N_NODES + 255) / 256;   // 196

__device__ __forceinline__ unsigned pack_bf16(float a, float b) {
    // round-to-nearest-even f32 -> bf16, packed low/high
    unsigned ua = __float_as_uint(a);
    unsigned ub = __float_as_uint(b);
    ua += 0x7fffu + ((ua >> 16) & 1u);
    ub += 0x7fffu + ((ub >> 16) & 1u);
    return (ua >> 16) | (ub & 0xffff0000u);
}
__device__ __forceinline__ float blo(unsigned u) { return __uint_as_float(u << 16); }
__device__ __forceinline__ float bhi(unsigned u) { return __uint_as_float(u & 0xffff0000u); }

// ---- GEMM: h = X @ W (bf16 out) + fused attn s/d epilogue ----
template<int H>
__global__ __launch_bounds__(256) void gemm128_k(
    const float* __restrict__ X, const float* __restrict__ W,
    unsigned short* __restrict__ Hb, int nrows,
    const float* __restrict__ a_src, const float* __restrict__ a_dst,
    float* __restrict__ sb, float* __restrict__ db)
{
    __shared__ float Ws[64][128];    // [k][col]
    __shared__ float XsT[64][128];   // [k][row]
    const int t  = threadIdx.x;
    const int tx = t & 15;
    const int ty = t >> 4;
    const int row0 = blockIdx.x * 128;

    float acc[8][8];
    #pragma unroll
    for (int i = 0; i < 8; ++i)
        #pragma unroll
        for (int j = 0; j < 8; ++j) acc[i][j] = 0.f;

    for (int kh = 0; kh < 2; ++kh) {
        const float4* Wv = (const float4*)(W + (size_t)kh * 64 * 128);
        float4* Wsv = (float4*)&Ws[0][0];
        #pragma unroll
        for (int i = 0; i < 8; ++i) Wsv[t + 256 * i] = Wv[t + 256 * i];
        #pragma unroll
        for (int ii = 0; ii < 8; ++ii) {
            int idx = t + 256 * ii;
            int r   = idx & 127;
            int q   = idx >> 7;
            int gr  = row0 + r;
            float4 v = make_float4(0.f, 0.f, 0.f, 0.f);
            if (gr < nrows) v = *(const float4*)(X + (size_t)gr * 128 + kh * 64 + q * 4);
            XsT[q * 4 + 0][r] = v.x;
            XsT[q * 4 + 1][r] = v.y;
            XsT[q * 4 + 2][r] = v.z;
            XsT[q * 4 + 3][r] = v.w;
        }
        __syncthreads();
        #pragma unroll 4
        for (int k = 0; k < 64; ++k) {
            float4 a0 = *(const float4*)&XsT[k][ty * 8];
            float4 a1 = *(const float4*)&XsT[k][ty * 8 + 4];
            float4 b0 = *(const float4*)&Ws[k][tx * 8];
            float4 b1 = *(const float4*)&Ws[k][tx * 8 + 4];
            float av[8] = {a0.x, a0.y, a0.z, a0.w, a1.x, a1.y, a1.z, a1.w};
            float bv[8] = {b0.x, b0.y, b0.z, b0.w, b1.x, b1.y, b1.z, b1.w};
            #pragma unroll
            for (int i = 0; i < 8; ++i)
                #pragma unroll
                for (int j = 0; j < 8; ++j)
                    acc[i][j] = fmaf(av[i], bv[j], acc[i][j]);
        }
        __syncthreads();
    }
    // store h as bf16 (only consumer is the gather in gat_fused_k)
    #pragma unroll
    for (int i = 0; i < 8; ++i) {
        int gr = row0 + ty * 8 + i;
        if (gr < nrows) {
            uint4 u;
            u.x = pack_bf16(acc[i][0], acc[i][1]);
            u.y = pack_bf16(acc[i][2], acc[i][3]);
            u.z = pack_bf16(acc[i][4], acc[i][5]);
            u.w = pack_bf16(acc[i][6], acc[i][7]);
            *(uint4*)(Hb + (size_t)gr * 128 + tx * 8) = u;
        }
    }
    // fused attn coefficients from fp32 acc (full precision)
    float as_c[8], ad_c[8];
    #pragma unroll
    for (int j = 0; j < 8; ++j) {
        as_c[j] = a_src[tx * 8 + j];
        ad_c[j] = a_dst[tx * 8 + j];
    }
    #pragma unroll
    for (int i = 0; i < 8; ++i) {
        float sp = 0.f, dp = 0.f;
        #pragma unroll
        for (int j = 0; j < 8; ++j) {
            sp = fmaf(acc[i][j], as_c[j], sp);
            dp = fmaf(acc[i][j], ad_c[j], dp);
        }
        int gr = row0 + ty * 8 + i;
        if (H == 4) {
            sp += __shfl_xor(sp, 1, 64); sp += __shfl_xor(sp, 2, 64);
            dp += __shfl_xor(dp, 1, 64); dp += __shfl_xor(dp, 2, 64);
            if ((tx & 3) == 0 && gr < nrows) {
                sb[gr * 4 + (tx >> 2)] = sp;
                db[gr * 4 + (tx >> 2)] = dp;
            }
        } else {
            sp += __shfl_xor(sp, 1, 64); sp += __shfl_xor(sp, 2, 64);
            sp += __shfl_xor(sp, 4, 64); sp += __shfl_xor(sp, 8, 64);
            dp += __shfl_xor(dp, 1, 64); dp += __shfl_xor(dp, 2, 64);
            dp += __shfl_xor(dp, 4, 64); dp += __shfl_xor(dp, 8, 64);
            if (tx == 0 && gr < nrows) { sb[gr] = sp; db[gr] = dp; }
        }
    }
}

__device__ __forceinline__ void edge_endpoints(const int* __restrict__ ei, int e,
                                               int& src, int& dst)
{
    if (e < E_RAW) { src = ei[e]; dst = ei[E_RAW + e]; }
    else           { src = e - E_RAW; dst = src; }
}

// ============ CSR build (once per call) ============
__global__ __launch_bounds__(256) void csr_count_k(
    const int* __restrict__ ei, int* __restrict__ cnt)
{
    int e = blockIdx.x * 256 + threadIdx.x;
    if (e >= E_TOT) return;
    int src, dst;
    edge_endpoints(ei, e, src, dst);
    atomicAdd(&cnt[dst], 1);
}

__device__ __forceinline__ int block_incl_scan_256(int x, int* wsum) {
    int lane = threadIdx.x & 63, wid = threadIdx.x >> 6;
    #pragma unroll
    for (int off = 1; off < 64; off <<= 1) {
        int y = __shfl_up(x, off, 64);
        if (lane >= off) x += y;
    }
    if (lane == 63) wsum[wid] = x;
    __syncthreads();
    int add = 0;
    #pragma unroll
    for (int w = 0; w < 4; ++w) if (w < wid) add += wsum[w];
    return x + add;
}

__global__ __launch_bounds__(256) void scan1_k(
    const int* __restrict__ cnt, int* __restrict__ rp, int* __restrict__ bsum)
{
    __shared__ int wsum[4];
    int i = blockIdx.x * 256 + threadIdx.x;
    int x = (i < N_NODES) ? cnt[i] : 0;
    int incl = block_incl_scan_256(x, wsum);
    if (i < N_NODES) rp[i] = incl;
    if (threadIdx.x == 255) bsum[blockIdx.x] = incl;
}

__global__ __launch_bounds__(256) void scan2_k(int* __restrict__ bsum)
{
    __shared__ int wsum[4];
    int t = threadIdx.x;
    int x = (t < SCAN_BLOCKS) ? bsum[t] : 0;
    int incl = block_incl_scan_256(x, wsum);
    if (t < SCAN_BLOCKS) bsum[t] = incl - x;   // exclusive
}

__global__ __launch_bounds__(256) void scan3_k(
    const int* __restrict__ cnt, int* __restrict__ rp,
    const int* __restrict__ bsum, int* __restrict__ cursor)
{
    int i = blockIdx.x * 256 + threadIdx.x;
    if (i < N_NODES) {
        int v = rp[i] + bsum[blockIdx.x] - cnt[i];
        rp[i] = v;
        cursor[i] = v;
    }
    if (i == 0) rp[N_NODES] = E_TOT;
}

__global__ __launch_bounds__(256) void csr_scatter_k(
    const int* __restrict__ ei, int* __restrict__ cursor, int* __restrict__ csr_src)
{
    int e = blockIdx.x * 256 + threadIdx.x;
    if (e >= E_TOT) return;
    int src, dst;
    edge_endpoints(ei, e, src, dst);
    int pos = atomicAdd(&cursor[dst], 1);
    csr_src[pos] = src;
}

// ============ fused per-destination GAT aggregation (bf16 h gather) ============
// phase 1: exact per-head max; phase 2: 8 edge-slots x 16 lanes, 16B bf16x8
// loads, branch-free exp + fp32 accumulate.
template<int H, bool RELU>
__global__ __launch_bounds__(128) void gat_fused_k(
    const int* __restrict__ rp, const int* __restrict__ csr_src,
    const unsigned short* __restrict__ Hb, const float* __restrict__ sb,
    const float* __restrict__ db, const float* __restrict__ bias,
    float* __restrict__ outv)
{
    constexpr int C = 128 / H;
    const int n = blockIdx.x;
    const int t = threadIdx.x;
    const int beg = rp[n], end = rp[n + 1];

    float dn[H];
    #pragma unroll
    for (int h = 0; h < H; ++h) dn[h] = db[n * H + h];

    // ---- phase 1: exact per-head max ----
    float mh[H];
    #pragma unroll
    for (int h = 0; h < H; ++h) mh[h] = -3.0e38f;
    for (int i = beg + t; i < end; i += 128) {
        int s = csr_src[i];
        if (H == 4) {
            float4 s4 = ((const float4*)sb)[s];
            float v0 = s4.x + dn[0], v1 = s4.y + dn[1];
            float v2 = s4.z + dn[2], v3 = s4.w + dn[3];
            v0 = v0 > 0.f ? v0 : SLOPE * v0;  v1 = v1 > 0.f ? v1 : SLOPE * v1;
            v2 = v2 > 0.f ? v2 : SLOPE * v2;  v3 = v3 > 0.f ? v3 : SLOPE * v3;
            mh[0] = fmaxf(mh[0], v0); mh[1] = fmaxf(mh[1], v1);
            mh[2] = fmaxf(mh[2], v2); mh[3] = fmaxf(mh[3], v3);
        } else {
            float v = sb[s] + dn[0];
            v = v > 0.f ? v : SLOPE * v;
            mh[0] = fmaxf(mh[0], v);
        }
    }
    #pragma unroll
    for (int off = 32; off >= 1; off >>= 1)
        #pragma unroll
        for (int h = 0; h < H; ++h)
            mh[h] = fmaxf(mh[h], __shfl_xor(mh[h], off, 64));
    __shared__ float mred[2][H];
    if ((t & 63) == 0) {
        #pragma unroll
        for (int h = 0; h < H; ++h) mred[t >> 6][h] = mh[h];
    }
    __syncthreads();

    // ---- phase 2: 8 edge streams, 16 lanes x 8 channels each ----
    const int f    = t & 15;          // channel group: f*8 .. f*8+7
    const int slot = t >> 4;          // 8 independent edge streams
    const int h    = (f * 8) / C;
    const float m  = fmaxf(mred[0][h], mred[1][h]);
    const float dnh = dn[h];

    float a0 = 0.f, a1 = 0.f, a2 = 0.f, a3 = 0.f;
    float a4 = 0.f, a5 = 0.f, a6 = 0.f, a7 = 0.f;
    float den = 0.f;
    for (int i = beg + slot; i < end; i += 8) {
        int s = csr_src[i];
        float e = sb[s * H + h] + dnh;
        e = e > 0.f ? e : SLOPE * e;
        float p = __expf(e - m);
        den += p;
        uint4 hv = *(const uint4*)(Hb + (size_t)s * 128 + f * 8);
        a0 = fmaf(p, blo(hv.x), a0);  a1 = fmaf(p, bhi(hv.x), a1);
        a2 = fmaf(p, blo(hv.y), a2);  a3 = fmaf(p, bhi(hv.y), a3);
        a4 = fmaf(p, blo(hv.z), a4);  a5 = fmaf(p, bhi(hv.z), a5);
        a6 = fmaf(p, blo(hv.w), a6);  a7 = fmaf(p, bhi(hv.w), a7);
    }
    // reduce slots within wave: wave0 holds slots 0-3, wave1 slots 4-7
    #pragma unroll
    for (int off = 16; off < 64; off <<= 1) {
        a0 += __shfl_xor(a0, off, 64); a1 += __shfl_xor(a1, off, 64);
        a2 += __shfl_xor(a2, off, 64); a3 += __shfl_xor(a3, off, 64);
        a4 += __shfl_xor(a4, off, 64); a5 += __shfl_xor(a5, off, 64);
        a6 += __shfl_xor(a6, off, 64); a7 += __shfl_xor(a7, off, 64);
        den += __shfl_xor(den, off, 64);
    }
    // cross-wave combine via LDS
    __shared__ float sacc[16][8];
    __shared__ float sden[16];
    if (t >= 64 && t < 80) {
        int ff = t - 64;
        sacc[ff][0] = a0; sacc[ff][1] = a1; sacc[ff][2] = a2; sacc[ff][3] = a3;
        sacc[ff][4] = a4; sacc[ff][5] = a5; sacc[ff][6] = a6; sacc[ff][7] = a7;
        sden[ff] = den;
    }
    __syncthreads();
    if (t < 16) {
        float inv = 1.f / (den + sden[t] + EPS_V);
        float o0 = (a0 + sacc[t][0]) * inv + bias[t * 8 + 0];
        float o1 = (a1 + sacc[t][1]) * inv + bias[t * 8 + 1];
        float o2 = (a2 + sacc[t][2]) * inv + bias[t * 8 + 2];
        float o3 = (a3 + sacc[t][3]) * inv + bias[t * 8 + 3];
        float o4 = (a4 + sacc[t][4]) * inv + bias[t * 8 + 4];
        float o5 = (a5 + sacc[t][5]) * inv + bias[t * 8 + 5];
        float o6 = (a6 + sacc[t][6]) * inv + bias[t * 8 + 6];
        float o7 = (a7 + sacc[t][7]) * inv + bias[t * 8 + 7];
        if (RELU) {
            o0 = fmaxf(o0, 0.f); o1 = fmaxf(o1, 0.f);
            o2 = fmaxf(o2, 0.f); o3 = fmaxf(o3, 0.f);
            o4 = fmaxf(o4, 0.f); o5 = fmaxf(o5, 0.f);
            o6 = fmaxf(o6, 0.f); o7 = fmaxf(o7, 0.f);
        }
        float* op = outv + (size_t)n * 128 + t * 8;
        *(float4*)(op)     = make_float4(o0, o1, o2, o3);
        *(float4*)(op + 4) = make_float4(o4, o5, o6, o7);
    }
}

template<int H, bool RELU>
void run_layer(const float* xin, const float* Wm, const float* as_, const float* ad_,
               const float* bias, const int* rp, const int* csr_src,
               unsigned short* hbuf, float* outv, float* sb, float* db,
               hipStream_t stream)
{
    gemm128_k<H><<<(N_NODES + 127) / 128, 256, 0, stream>>>(
        xin, Wm, hbuf, N_NODES, as_, ad_, sb, db);
    gat_fused_k<H, RELU><<<N_NODES, 128, 0, stream>>>(rp, csr_src, hbuf, sb, db, bias, outv);
}

} // namespace

extern "C" void kernel_launch(void* const* d_in, const int* in_sizes, int n_in,
                              void* d_out, int out_size, void* d_ws, size_t ws_size,
                              hipStream_t stream)
{
    (void)in_sizes; (void)n_in; (void)out_size; (void)ws_size;
    const float* x   = (const float*)d_in[0];
    const int*   ei  = (const int*)d_in[1];
    const float* W0  = (const float*)d_in[2];
    const float* as0 = (const float*)d_in[3];
    const float* ad0 = (const float*)d_in[4];
    const float* b0  = (const float*)d_in[5];
    const float* W1  = (const float*)d_in[6];
    const float* as1 = (const float*)d_in[7];
    const float* ad1 = (const float*)d_in[8];
    const float* b1  = (const float*)d_in[9];
    const float* W2  = (const float*)d_in[10];
    const float* as2 = (const float*)d_in[11];
    const float* ad2 = (const float*)d_in[12];
    const float* b2  = (const float*)d_in[13];
    float* out = (float*)d_out;

    char* p = (char*)d_ws;
    unsigned short* Hb = (unsigned short*)p;  p += (size_t)N_NODES * 128 * 2;  // bf16 h
    float* B       = (float*)p;  p += (size_t)N_NODES * 128 * 4;   // x1 / scratch
    float* sb      = (float*)p;  p += (size_t)N_NODES * 4 * 4;
    float* db      = (float*)p;  p += (size_t)N_NODES * 4 * 4;
    int*   cnt     = (int*)p;    p += (size_t)N_NODES * 4;
    int*   rp      = (int*)p;    p += (size_t)(N_NODES + 1) * 4;
    int*   cursor  = (int*)p;    p += (size_t)N_NODES * 4;
    int*   bsum    = (int*)p;    p += (size_t)SCAN_BLOCKS * 4;
    int*   csr_src = (int*)p;    p += (size_t)E_TOT * 4;

    const int EB = (E_TOT + 255) / 256;

    // ---- CSR build (once; reused by all 3 layers) ----
    hipMemsetAsync(cnt, 0, (size_t)N_NODES * 4, stream);
    csr_count_k<<<EB, 256, 0, stream>>>(ei, cnt);
    scan1_k<<<SCAN_BLOCKS, 256, 0, stream>>>(cnt, rp, bsum);
    scan2_k<<<1, 256, 0, stream>>>(bsum);
    scan3_k<<<SCAN_BLOCKS, 256, 0, stream>>>(cnt, rp, bsum, cursor);
    csr_scatter_k<<<EB, 256, 0, stream>>>(ei, cursor, csr_src);

    // Layer 0: x -> h(Hb bf16); fused agg -> B (ReLU)
    run_layer<4, true >(x,   W0, as0, ad0, b0, rp, csr_src, Hb, B,   sb, db, stream);
    // Layer 1: B -> h(Hb); fused agg -> out (ReLU)
    run_layer<4, true >(B,   W1, as1, ad1, b1, rp, csr_src, Hb, out, sb, db, stream);
    // Layer 2 (H=1): out -> h(Hb); fused agg -> out (no ReLU)
    run_layer<1, false>(out, W2, as2, ad2, b2, rp, csr_src, Hb, out, sb, db, stream);
}